// Round 14
// baseline (185.489 us; speedup 1.0000x reference)
//
#include <hip/hip_runtime.h>
#include <math.h>

// Shapes: B=8, T=16, H=64, W=64, D=256, DK=128, TOP_K=4
// pixels N = B*H*W = 32768 (4096 per batch)
//
// Factorization: out = (sum_t attn_t * hist_t) @ (Wv@Wo)
//                score_t = (q @ (Wq@Wk^T)) . hist_t / sqrt(128)
// Score path fp32 (top-k precision-critical); out-projection bf16 MFMA.
//
// R14: stream goes T-MAJOR with exact ONLINE top-4. Per wave: 4 adjacent
// pixels per group; each t-step issues ONE 4KB-contiguous 4-load run
// (page/channel-local, vs 16 loads at 4MiB stride) and updates per-pixel
// running top-4 {score,t,h} in registers. Kills the rank pass and the
// 16-term hbar (winners' h already resident). Insert rule strict-greater
// == lax.top_k lowest-index tie-break.

typedef __attribute__((ext_vector_type(8))) short bf16x8;
typedef __attribute__((ext_vector_type(4))) float f32x4;

__device__ inline unsigned short f2bf(float f) {
  union { float f; unsigned u; } v; v.f = f;
  unsigned r = (v.u + 0x7FFF + ((v.u >> 16) & 1)) >> 16;  // RNE
  return (unsigned short)r;
}

// ---------------- Kernel P: M1 = Wq@Wk^T, M2F = bf16-frag(Wv@Wo) ----------
__global__ __launch_bounds__(256) void precompute_weights(
    const float* __restrict__ Wq, const float* __restrict__ Wk,
    const float* __restrict__ Wv, const float* __restrict__ Wo,
    float* __restrict__ M1, unsigned short* __restrict__ M2F) {
  __shared__ float rowbuf[128];
  int bid = blockIdx.x, tid = threadIdx.x;
  if (bid < 256) {
    if (tid < 128) rowbuf[tid] = Wq[bid * 128 + tid];
    __syncthreads();
    const float4* Wk4 = (const float4*)Wk;
    const float4* rb4 = (const float4*)rowbuf;
    float acc = 0.f;
#pragma unroll 8
    for (int k4 = 0; k4 < 32; ++k4) {
      float4 a = rb4[k4];
      float4 b = Wk4[tid * 32 + k4];
      acc = fmaf(a.x, b.x, acc); acc = fmaf(a.y, b.y, acc);
      acc = fmaf(a.z, b.z, acc); acc = fmaf(a.w, b.w, acc);
    }
    M1[bid * 256 + tid] = acc;
  } else {
    int k = bid - 256;  // M2 row index
    if (tid < 128) rowbuf[tid] = Wv[k * 128 + tid];
    __syncthreads();
    float acc = 0.f;
#pragma unroll 8
    for (int kk = 0; kk < 128; ++kk)
      acc = fmaf(rowbuf[kk], Wo[kk * 256 + tid], acc);
    // MFMA B-frag layout: frag(ct,kt): lane l holds
    // B[kt*32 + (l>>4)*8 + i][ct*16 + (l&15)]
    int c = tid;
    int ct = c >> 4, kt = k >> 5, lh = (k >> 3) & 3, i = k & 7, lm = c & 15;
    M2F[(size_t)(((ct * 8 + kt) * 64 + lh * 16 + lm) * 8 + i)] = f2bf(acc);
  }
}

// ---------------- Mega-kernel: qm -> online attention -> MFMA out ---------
// 64 pixels/block, 4 waves, wave w owns rows r0=w*16 .. r0+15. NO barriers.
__global__ __launch_bounds__(256, 2) void fused_all(
    const float* __restrict__ query, const float* __restrict__ hist,
    const float* __restrict__ M1, const unsigned short* __restrict__ M2F,
    float* __restrict__ OUT) {
  __shared__ float As[64][260];  // per-wave 16-row slice: query->qm->hbar
  int tid = threadIdx.x;
  int l = tid & 63;   // lane
  int w = tid >> 6;   // wave
  int pix0 = blockIdx.x * 64;
  int r0 = w * 16;

  const float4* H4 = (const float4*)hist;
  int b = pix0 >> 12;
  int off0 = pix0 & 4095;
  // float4 index: b*4194304 + t*262144 + (off0+r0+4g+j)*64 + l
  size_t habase = ((size_t)b * 65536 + off0 + r0) * 64 + l;

  float4 hA[4], hB[4];
  // prefetch group 0, t=0 (lands under phase 0)
#pragma unroll
  for (int j = 0; j < 4; ++j) hA[j] = H4[habase + (size_t)j * 64];

  // ---------- phase 0: own 16 rows of qm = query @ M1 (fp32) ----------
  {
    const float4* Qb4 = (const float4*)(query + (size_t)pix0 * 256);
#pragma unroll
    for (int k = 0; k < 16; ++k)
      *(float4*)&As[r0 + k][4 * l] = Qb4[(size_t)(r0 + k) * 64 + l];
    float4 acc[16];
#pragma unroll
    for (int j = 0; j < 16; ++j) acc[j] = make_float4(0.f, 0.f, 0.f, 0.f);
    const float4* B4 = (const float4*)M1;
#pragma unroll 4
    for (int d = 0; d < 256; ++d) {
      float4 bv = B4[d * 64 + l];
#pragma unroll
      for (int j = 0; j < 16; ++j) {
        float a = As[r0 + j][d];  // uniform -> LDS broadcast
        acc[j].x = fmaf(a, bv.x, acc[j].x);
        acc[j].y = fmaf(a, bv.y, acc[j].y);
        acc[j].z = fmaf(a, bv.z, acc[j].z);
        acc[j].w = fmaf(a, bv.w, acc[j].w);
      }
    }
#pragma unroll
    for (int j = 0; j < 16; ++j)
      *(float4*)&As[r0 + j][4 * l] = acc[j];
  }

  // ---------- phase 1: t-major stream + online exact top-4 ----------
#define STEP(HC, HN, T, PRE, NG4, NT)                                       \
  {                                                                         \
    if (PRE) {                                                              \
      _Pragma("unroll") for (int j = 0; j < 4; ++j)                         \
          HN[j] = H4[habase + (size_t)((NG4) + j) * 64 +                    \
                     (size_t)(NT)*262144];                                  \
    }                                                                       \
    float pp[4];                                                            \
    _Pragma("unroll") for (int j = 0; j < 4; ++j) {                         \
      float s = HC[j].x * q[j].x;                                           \
      s = fmaf(HC[j].y, q[j].y, s);                                         \
      s = fmaf(HC[j].z, q[j].z, s);                                         \
      s = fmaf(HC[j].w, q[j].w, s);                                         \
      pp[j] = s;                                                            \
    }                                                                       \
    float sc[4];                                                            \
    {                                                                       \
      bool h1 = l & 1;                                                      \
      float m0 = h1 ? pp[1] : pp[0], o0 = h1 ? pp[0] : pp[1];               \
      float r0v = m0 + __shfl_xor(o0, 1);                                   \
      float m1 = h1 ? pp[3] : pp[2], o1 = h1 ? pp[2] : pp[3];               \
      float r1v = m1 + __shfl_xor(o1, 1);                                   \
      bool h2 = l & 2;                                                      \
      float m2 = h2 ? r1v : r0v, o2 = h2 ? r0v : r1v;                       \
      float rr = m2 + __shfl_xor(o2, 2);                                    \
      rr += __shfl_xor(rr, 4);                                              \
      rr += __shfl_xor(rr, 8);                                              \
      rr += __shfl_xor(rr, 16);                                             \
      rr += __shfl_xor(rr, 32);                                             \
      rr *= 0.08838834764831845f; /* 1/sqrt(128) */                         \
      _Pragma("unroll") for (int j = 0; j < 4; ++j)                         \
          sc[j] = __shfl(rr, (l & 60) | j);                                 \
    }                                                                       \
    _Pragma("unroll") for (int j = 0; j < 4; ++j) {                         \
      if ((T) < 4) { /* fill slots */                                       \
        ss[j][(T)] = sc[j]; stf[j][(T)] = (float)(T); sh[j][(T)] = HC[j];   \
      } else { /* exact online top-4: strict-greater replaces worst */      \
        float ms = ss[j][0], mt = stf[j][0]; int m = 0;                     \
        _Pragma("unroll") for (int k = 1; k < 4; ++k) {                     \
          bool wse = (ss[j][k] < ms) || (ss[j][k] == ms && stf[j][k] > mt); \
          if (wse) { m = k; ms = ss[j][k]; mt = stf[j][k]; }                \
        }                                                                   \
        if (sc[j] > ms) { /* wave-uniform branch */                         \
          _Pragma("unroll") for (int k = 0; k < 4; ++k)                     \
              if (m == k) {                                                 \
            ss[j][k] = sc[j]; stf[j][k] = (float)(T); sh[j][k] = HC[j];     \
          }                                                                 \
        }                                                                   \
      }                                                                     \
    }                                                                       \
  }

  for (int g = 0; g < 4; ++g) {
    int g4 = g * 4;
    float4 q[4];
#pragma unroll
    for (int j = 0; j < 4; ++j)
      q[j] = *(const float4*)&As[r0 + g4 + j][4 * l];
    float ss[4][4], stf[4][4];
    float4 sh[4][4];

    STEP(hA, hB, 0, 1, g4, 1)
    STEP(hB, hA, 1, 1, g4, 2)
    STEP(hA, hB, 2, 1, g4, 3)
    STEP(hB, hA, 3, 1, g4, 4)
    STEP(hA, hB, 4, 1, g4, 5)
    STEP(hB, hA, 5, 1, g4, 6)
    STEP(hA, hB, 6, 1, g4, 7)
    STEP(hB, hA, 7, 1, g4, 8)
    STEP(hA, hB, 8, 1, g4, 9)
    STEP(hB, hA, 9, 1, g4, 10)
    STEP(hA, hB, 10, 1, g4, 11)
    STEP(hB, hA, 11, 1, g4, 12)
    STEP(hA, hB, 12, 1, g4, 13)
    STEP(hB, hA, 13, 1, g4, 14)
    STEP(hA, hB, 14, 1, g4, 15)
    STEP(hB, hA, 15, (g < 3), g4 + 4, 0)  // prefetch next group's t=0

    // finalize group: decay bias + softmax over the 4 winners, hbar
#pragma unroll
    for (int j = 0; j < 4; ++j) {
      float e0 = expf(ss[j][0] + (16.f - stf[j][0]) * -0.05129329438755058f);
      float e1 = expf(ss[j][1] + (16.f - stf[j][1]) * -0.05129329438755058f);
      float e2 = expf(ss[j][2] + (16.f - stf[j][2]) * -0.05129329438755058f);
      float e3 = expf(ss[j][3] + (16.f - stf[j][3]) * -0.05129329438755058f);
      float iZ = 1.0f / (e0 + e1 + e2 + e3);
      float a0 = e0 * iZ, a1 = e1 * iZ, a2 = e2 * iZ, a3 = e3 * iZ;
      float4 hb;
      hb.x = a0 * sh[j][0].x; hb.y = a0 * sh[j][0].y;
      hb.z = a0 * sh[j][0].z; hb.w = a0 * sh[j][0].w;
      hb.x = fmaf(a1, sh[j][1].x, hb.x); hb.y = fmaf(a1, sh[j][1].y, hb.y);
      hb.z = fmaf(a1, sh[j][1].z, hb.z); hb.w = fmaf(a1, sh[j][1].w, hb.w);
      hb.x = fmaf(a2, sh[j][2].x, hb.x); hb.y = fmaf(a2, sh[j][2].y, hb.y);
      hb.z = fmaf(a2, sh[j][2].z, hb.z); hb.w = fmaf(a2, sh[j][2].w, hb.w);
      hb.x = fmaf(a3, sh[j][3].x, hb.x); hb.y = fmaf(a3, sh[j][3].y, hb.y);
      hb.z = fmaf(a3, sh[j][3].z, hb.z); hb.w = fmaf(a3, sh[j][3].w, hb.w);
      *(float4*)&As[r0 + g4 + j][4 * l] = hb;  // row wave-owned
    }
  }
#undef STEP

  // ---------- phase 2: OUT rows r0..r0+15 = As(hbar) @ M2 via bf16 MFMA ---
  {
    int lm = l & 15, lh = l >> 4;
    const bf16x8* B8 = (const bf16x8*)M2F;
    f32x4 acc[16];
#pragma unroll
    for (int ct = 0; ct < 16; ++ct) acc[ct] = (f32x4){0.f, 0.f, 0.f, 0.f};
#pragma unroll
    for (int kt = 0; kt < 8; ++kt) {
      const float* ap = &As[r0 + lm][kt * 32 + lh * 8];
      float4 a0 = *(const float4*)ap;
      float4 a1 = *(const float4*)(ap + 4);
      bf16x8 afrag;
      afrag[0] = (short)f2bf(a0.x); afrag[1] = (short)f2bf(a0.y);
      afrag[2] = (short)f2bf(a0.z); afrag[3] = (short)f2bf(a0.w);
      afrag[4] = (short)f2bf(a1.x); afrag[5] = (short)f2bf(a1.y);
      afrag[6] = (short)f2bf(a1.z); afrag[7] = (short)f2bf(a1.w);
#pragma unroll
      for (int ct = 0; ct < 16; ++ct) {
        bf16x8 bfrag = B8[(ct * 8 + kt) * 64 + l];
        acc[ct] = __builtin_amdgcn_mfma_f32_16x16x32_bf16(afrag, bfrag,
                                                          acc[ct], 0, 0, 0);
      }
    }
    float* outp = OUT + (size_t)pix0 * 256;
#pragma unroll
    for (int ct = 0; ct < 16; ++ct) {
#pragma unroll
      for (int j = 0; j < 4; ++j)
        outp[(size_t)(r0 + lh * 4 + j) * 256 + ct * 16 + lm] = acc[ct][j];
    }
  }
}

// --------------------------------------------------------------------------
extern "C" void kernel_launch(void* const* d_in, const int* in_sizes, int n_in,
                              void* d_out, int out_size, void* d_ws,
                              size_t ws_size, hipStream_t stream) {
  const float* query = (const float*)d_in[0];  // [8,64,64,256]
  const float* hist = (const float*)d_in[1];   // [8,16,64,64,256]
  const float* Wq = (const float*)d_in[2];     // [256,128]
  const float* Wk = (const float*)d_in[3];     // [256,128]
  const float* Wv = (const float*)d_in[4];     // [256,128]
  const float* Wo = (const float*)d_in[5];     // [128,256]
  float* out = (float*)d_out;                  // [32768,256]

  float* ws = (float*)d_ws;
  float* M1 = ws;  // 65536 floats
  unsigned short* M2F = (unsigned short*)(ws + 65536);  // bf16 frag order

  precompute_weights<<<512, 256, 0, stream>>>(Wq, Wk, Wv, Wo, M1, M2F);
  fused_all<<<512, 256, 0, stream>>>(query, hist, M1, M2F, out);
}